// Round 1
// baseline (451.622 us; speedup 1.0000x reference)
//
#include <hip/hip_runtime.h>
#include <math.h>

#define EPS  1e-5f
#define EPS2 1e-10f
#define MAXN (1.0f - EPS)

// ---------- block reduction helpers (256 threads = 4 waves) ----------
static __device__ __forceinline__ float block_sum(float v, float* red4) {
#pragma unroll
  for (int m = 32; m; m >>= 1) v += __shfl_xor(v, m, 64);
  if ((threadIdx.x & 63) == 0) red4[threadIdx.x >> 6] = v;
  __syncthreads();
  v = red4[0] + red4[1] + red4[2] + red4[3];
  __syncthreads();
  return v;
}

// ---------- K1: x -> logmap0(project(x))  (row norm over 512) ----------
// layout 0: src row-major [n,512]; layout 1: gather from [B,H,S,D]
__global__ __launch_bounds__(256) void k_logmap(const float* __restrict__ s0,
                                                const float* __restrict__ s1,
                                                const float* __restrict__ s2,
                                                float* __restrict__ dst, int layout) {
  const int n = blockIdx.x, z = blockIdx.y, t = threadIdx.x;
  const float* src = (z == 0) ? s0 : ((z == 1) ? s1 : s2);
  const int e0 = t * 2;
  float2 xv;
  if (layout == 0) {
    xv = *(const float2*)&src[(size_t)n * 512 + e0];
  } else {
    const int b = n >> 9, s = n & 511, h = e0 >> 6, d = e0 & 63;
    xv = *(const float2*)&src[(((size_t)(b * 8 + h) * 512 + s) * 64 + d)];
  }
  __shared__ float red4[4];
  const float ss = block_sum(xv.x * xv.x + xv.y * xv.y, red4);
  const float r = sqrtf(fmaxf(ss, EPS2));
  float f;
  if (r >= MAXN) {
    // projected: n = (1-EPS)r/(r+EPS); stable atanh avoids 1-n cancellation
    const float at = 0.5f * logf((r * (2.0f - EPS) + EPS) / (EPS * (1.0f + r)));
    f = (1.0f + EPS) * at / r;           // includes scale/n = 1/r
  } else {
    const float at = 0.5f * logf((1.0f + r) / (1.0f - r));
    f = (1.0f + EPS) * at / r;           // r >= EPS via clamp
  }
  float2 o; o.x = f * xv.x; o.y = f * xv.y;
  *(float2*)&dst[((size_t)z * 2048 + n) * 512 + e0] = o;
}

// ---------- K2: C = A @ W^T ; A [2048,512], W [512,512] row-major ----------
__global__ __launch_bounds__(256) void k_gemm(const float* __restrict__ Abase,
                                              const float* __restrict__ W0,
                                              const float* __restrict__ W1,
                                              const float* __restrict__ W2,
                                              float* __restrict__ Cbase) {
  const int z = blockIdx.z;
  const float* A = Abase + (size_t)z * (2048 * 512);
  const float* W = (z == 0) ? W0 : ((z == 1) ? W1 : W2);
  float* C = Cbase + (size_t)z * (2048 * 512);
  __shared__ __align__(16) float As[32][68];   // k-major, pad 68 kills conflicts
  __shared__ __align__(16) float Ws[32][68];
  const int t = threadIdx.x;
  const int n0 = blockIdx.x * 64, m0 = blockIdx.y * 64;
  const int tx = t & 15, ty = t >> 4;
  const int lr = t >> 3, lk = (t & 7) * 4;
  float acc[4][4] = {};
  for (int k0 = 0; k0 < 512; k0 += 32) {
    const float4 a0 = *(const float4*)&A[(size_t)(n0 + lr) * 512 + k0 + lk];
    const float4 a1 = *(const float4*)&A[(size_t)(n0 + lr + 32) * 512 + k0 + lk];
    const float4 w0 = *(const float4*)&W[(size_t)(m0 + lr) * 512 + k0 + lk];
    const float4 w1 = *(const float4*)&W[(size_t)(m0 + lr + 32) * 512 + k0 + lk];
    __syncthreads();
    As[lk + 0][lr] = a0.x; As[lk + 1][lr] = a0.y; As[lk + 2][lr] = a0.z; As[lk + 3][lr] = a0.w;
    As[lk + 0][lr + 32] = a1.x; As[lk + 1][lr + 32] = a1.y; As[lk + 2][lr + 32] = a1.z; As[lk + 3][lr + 32] = a1.w;
    Ws[lk + 0][lr] = w0.x; Ws[lk + 1][lr] = w0.y; Ws[lk + 2][lr] = w0.z; Ws[lk + 3][lr] = w0.w;
    Ws[lk + 0][lr + 32] = w1.x; Ws[lk + 1][lr + 32] = w1.y; Ws[lk + 2][lr + 32] = w1.z; Ws[lk + 3][lr + 32] = w1.w;
    __syncthreads();
#pragma unroll
    for (int kk = 0; kk < 32; ++kk) {
      const float4 av = *(const float4*)&As[kk][ty * 4];
      const float4 wv = *(const float4*)&Ws[kk][tx * 4];
      const float a[4] = {av.x, av.y, av.z, av.w};
      const float b[4] = {wv.x, wv.y, wv.z, wv.w};
#pragma unroll
      for (int i = 0; i < 4; ++i)
#pragma unroll
        for (int j = 0; j < 4; ++j) acc[i][j] = fmaf(a[i], b[j], acc[i][j]);
    }
  }
#pragma unroll
  for (int i = 0; i < 4; ++i) {
    float4 st; st.x = acc[i][0]; st.y = acc[i][1]; st.z = acc[i][2]; st.w = acc[i][3];
    *(float4*)&C[(size_t)(n0 + ty * 4 + i) * 512 + m0 + tx * 4] = st;
  }
}

// ---------- K3: expmap0 + mobius-add bias; optional per-head project + norms ----------
// final_mode=0: write [B,H,S,D] per-head (z=0,1 projected + norm; z=2 raw + norm)
// final_mode=1: write row-major [n,512] to o0 (the final output)
__global__ __launch_bounds__(256) void k_post(const float* __restrict__ tin,
                                              const float* __restrict__ b0,
                                              const float* __restrict__ b1,
                                              const float* __restrict__ b2,
                                              float* __restrict__ o0, float* __restrict__ o1,
                                              float* __restrict__ o2,
                                              float* __restrict__ nrm0, float* __restrict__ nrm1,
                                              float* __restrict__ nrm2, int final_mode) {
  const int nrow = blockIdx.x, z = blockIdx.y, t = threadIdx.x;
  const float* tv = tin + ((size_t)z * 2048 + nrow) * 512;
  const float* bias = (z == 0) ? b0 : ((z == 1) ? b1 : b2);
  const int e0 = 2 * t;
  const float2 tp = *(const float2*)&tv[e0];
  const float2 bp = *(const float2*)&bias[e0];
  float p_tt = tp.x * tp.x + tp.y * tp.y;
  float p_tb = tp.x * bp.x + tp.y * bp.y;
  float p_bb = bp.x * bp.x + bp.y * bp.y;
#pragma unroll
  for (int m = 32; m; m >>= 1) {
    p_tt += __shfl_xor(p_tt, m, 64);
    p_tb += __shfl_xor(p_tb, m, 64);
    p_bb += __shfl_xor(p_bb, m, 64);
  }
  __shared__ float red[4][3];
  const int lane = t & 63, w = t >> 6;
  if (lane == 0) { red[w][0] = p_tt; red[w][1] = p_tb; red[w][2] = p_bb; }
  __syncthreads();
  const float s_tt = red[0][0] + red[1][0] + red[2][0] + red[3][0];
  const float s_tb = red[0][1] + red[1][1] + red[2][1] + red[3][1];
  const float s_bb = red[0][2] + red[1][2] + red[2][2] + red[3][2];
  // expmap0: r = tanh(n/(1+EPS)) * t / n, then project
  const float tn = sqrtf(fmaxf(s_tt, EPS2));
  const float th = tanhf(tn / (1.0f + EPS));
  const float g = th / tn;
  const float rnorm = th * (sqrtf(s_tt) / tn);
  const float sr = (rnorm >= MAXN) ? (MAXN / (rnorm + EPS)) : 1.0f;
  const float gr = g * sr;
  const float rn = (rnorm * sr) * (rnorm * sr);
  // mobius add with projected bias; output norm analytic (no 3rd reduction)
  const float bnorm = sqrtf(fmaxf(s_bb, EPS2));
  const float sb = (bnorm >= MAXN) ? (MAXN / (bnorm + EPS)) : 1.0f;
  const float xy = gr * sb * s_tb;
  const float yn = (sb * sb) * s_bb;
  const float Af = 1.0f + 2.0f * xy + yn;
  const float Cf = 1.0f - rn;
  const float den = 1.0f + 2.0f * xy + rn * yn + EPS;
  const float id = 1.0f / den;
  const float on_raw = (Af * Af * rn + 2.0f * Af * Cf * xy + Cf * Cf * yn) * (id * id);
  const float no = sqrtf(fmaxf(on_raw, EPS2));
  const float so = (no >= MAXN) ? (MAXN / (no + EPS)) : 1.0f;
  const float ms = id * so;
  const float ca = gr * Af * ms;
  const float cb = sb * Cf * ms;
  const float v0 = ca * tp.x + cb * bp.x;
  const float v1 = ca * tp.y + cb * bp.y;
  if (final_mode) {
    float2 o; o.x = v0; o.y = v1;
    *(float2*)&o0[(size_t)nrow * 512 + e0] = o;
    return;
  }
  // per-head (64-elem chunk) norm via 32-lane butterfly; q/k projected, v raw
  float hp = v0 * v0 + v1 * v1;
#pragma unroll
  for (int m = 16; m; m >>= 1) hp += __shfl_xor(hp, m, 64);
  const float hnr = sqrtf(fmaxf(hp, EPS2));
  float sh = 1.0f;
  if (z != 2) sh = (hnr >= MAXN) ? (MAXN / (hnr + EPS)) : 1.0f;
  float* outz = (z == 0) ? o0 : ((z == 1) ? o1 : o2);
  float* nz = (z == 0) ? nrm0 : ((z == 1) ? nrm1 : nrm2);
  const int b = nrow >> 9, s = nrow & 511, h = e0 >> 6, d = e0 & 63;
  float2 o; o.x = v0 * sh; o.y = v1 * sh;
  *(float2*)&outz[(((size_t)(b * 8 + h) * 512 + s) * 64 + d)] = o;
  if ((t & 31) == 0) nz[(size_t)(b * 8 + h) * 512 + s] = hp * sh * sh;
}

// ---------- K4: -dist logits [32,512,512] ----------
__global__ __launch_bounds__(256) void k_logits(const float* __restrict__ Q,
                                                const float* __restrict__ K,
                                                const float* __restrict__ qn,
                                                const float* __restrict__ kn,
                                                float* __restrict__ attn) {
  const int bh = blockIdx.z;
  const int i0 = blockIdx.x * 64;
  const int j0 = blockIdx.y * 128;
  const float* Qb = Q + (size_t)bh * 512 * 64;
  const float* Kb = K + (size_t)bh * 512 * 64;
  __shared__ __align__(16) float q_lds[64][68];
  __shared__ __align__(16) float k_lds[128][68];
  const int t = threadIdx.x;
  const int tx = t & 15, ty = t >> 4;
  const int tx4 = tx * 4;
#pragma unroll
  for (int it = 0; it < 4; ++it) {
    const int row = it * 16 + ty;
    *(float4*)&q_lds[row][tx4] = *(const float4*)&Qb[(size_t)(i0 + row) * 64 + tx4];
  }
#pragma unroll
  for (int it = 0; it < 8; ++it) {
    const int row = it * 16 + ty;
    *(float4*)&k_lds[row][tx4] = *(const float4*)&Kb[(size_t)(j0 + row) * 64 + tx4];
  }
  __syncthreads();
  float acc[4][8] = {};
#pragma unroll
  for (int d = 0; d < 64; d += 4) {
    float4 qv[4], kv[8];
#pragma unroll
    for (int i = 0; i < 4; ++i) qv[i] = *(const float4*)&q_lds[ty * 4 + i][d];
#pragma unroll
    for (int j = 0; j < 8; ++j) kv[j] = *(const float4*)&k_lds[tx + 16 * j][d];
#pragma unroll
    for (int i = 0; i < 4; ++i)
#pragma unroll
      for (int j = 0; j < 8; ++j) {
        acc[i][j] = fmaf(qv[i].x, kv[j].x, acc[i][j]);
        acc[i][j] = fmaf(qv[i].y, kv[j].y, acc[i][j]);
        acc[i][j] = fmaf(qv[i].z, kv[j].z, acc[i][j]);
        acc[i][j] = fmaf(qv[i].w, kv[j].w, acc[i][j]);
      }
  }
  float qni[4], knj[8];
#pragma unroll
  for (int i = 0; i < 4; ++i) qni[i] = qn[(size_t)bh * 512 + i0 + ty * 4 + i];
#pragma unroll
  for (int j = 0; j < 8; ++j) knj[j] = kn[(size_t)bh * 512 + j0 + tx + 16 * j];
#pragma unroll
  for (int i = 0; i < 4; ++i)
#pragma unroll
    for (int j = 0; j < 8; ++j) {
      const float num = fmaxf(qni[i] + knj[j] - 2.0f * acc[i][j], 0.0f);
      const float den = fmaxf((1.0f - qni[i]) * (1.0f - knj[j]), EPS);
      const float wv = 2.0f * num / den + EPS;
      // acosh(1+wv) = log(1+wv+sqrt(wv*(wv+2))) -- cancellation-free
      const float dist = logf(1.0f + wv + sqrtf(wv * (wv + 2.0f)));
      attn[((size_t)bh * 512 + i0 + ty * 4 + i) * 512 + j0 + tx + 16 * j] = -dist;
    }
}

// ---------- K5: in-place row softmax over 512 ----------
__global__ __launch_bounds__(256) void k_softmax(float* __restrict__ attn) {
  const int row = blockIdx.x, t = threadIdx.x;
  float* p = attn + (size_t)row * 512;
  const float2 x = *(const float2*)&p[2 * t];
  __shared__ float red4[4];
  float m = fmaxf(x.x, x.y);
#pragma unroll
  for (int mk = 32; mk; mk >>= 1) m = fmaxf(m, __shfl_xor(m, mk, 64));
  if ((t & 63) == 0) red4[t >> 6] = m;
  __syncthreads();
  m = fmaxf(fmaxf(red4[0], red4[1]), fmaxf(red4[2], red4[3]));
  __syncthreads();
  const float e0 = expf(x.x - m), e1 = expf(x.y - m);
  float s = e0 + e1;
#pragma unroll
  for (int mk = 32; mk; mk >>= 1) s += __shfl_xor(s, mk, 64);
  if ((t & 63) == 0) red4[t >> 6] = s;
  __syncthreads();
  s = red4[0] + red4[1] + red4[2] + red4[3];
  const float inv = 1.0f / s;
  float2 o; o.x = e0 * inv; o.y = e1 * inv;
  *(float2*)&p[2 * t] = o;
}

// ---------- K6: sequential mobius scan over 512 key positions ----------
// 8 lanes/row, 8 elems/lane; one analytic-norm trick -> single 3-shuffle dot per step
__global__ __launch_bounds__(256) void k_scan(const float* __restrict__ V,
                                              const float* __restrict__ vn,
                                              const float* __restrict__ attnw,
                                              float* __restrict__ att) {
  __shared__ __align__(16) float v_lds[128 * 64];
  __shared__ __align__(16) float a_lds[32 * 132];
  __shared__ float vn_lds[128];
  const int blk = blockIdx.x;
  const int bh = blk >> 4;
  const int i0 = (blk & 15) * 32;
  const int t = threadIdx.x, lane = t & 63, w = t >> 6;
  const int r = lane >> 3, d0 = (lane & 7) * 8;
  const int i_local = w * 8 + r;
  const float* Vb = V + (size_t)bh * 512 * 64;
  const float* ab = attnw + ((size_t)bh * 512 + i0) * 512;
  const float* vnb = vn + (size_t)bh * 512;
  float ws0 = 0, ws1 = 0, ws2 = 0, ws3 = 0, ws4 = 0, ws5 = 0, ws6 = 0, ws7 = 0;
  float xn = 0.0f;
  for (int jc = 0; jc < 512; jc += 128) {
#pragma unroll
    for (int it = 0; it < 8; ++it) {
      const int idx = it * 1024 + t * 4;
      *(float4*)&v_lds[idx] = *(const float4*)&Vb[(size_t)jc * 64 + idx];
    }
#pragma unroll
    for (int it = 0; it < 4; ++it) {
      const int idx = it * 1024 + t * 4;
      const int row = idx >> 7, c = idx & 127;
      *(float4*)&a_lds[row * 132 + c] = *(const float4*)&ab[(size_t)row * 512 + jc + c];
    }
    if (t < 128) vn_lds[t] = vnb[jc + t];
    __syncthreads();
#pragma unroll 4
    for (int j = 0; j < 128; ++j) {
      const float wgt = a_lds[i_local * 132 + j];
      const float vnj = vn_lds[j];
      const float4 va = *(const float4*)&v_lds[j * 64 + d0];
      const float4 vb = *(const float4*)&v_lds[j * 64 + d0 + 4];
      float pp = ws0 * va.x + ws1 * va.y + ws2 * va.z + ws3 * va.w +
                 ws4 * vb.x + ws5 * vb.y + ws6 * vb.z + ws7 * vb.w;
      pp += __shfl_xor(pp, 1, 64);
      pp += __shfl_xor(pp, 2, 64);
      pp += __shfl_xor(pp, 4, 64);            // dot(ws, v_j) across the 8-lane row
      const float yn_raw = wgt * wgt * vnj;   // ||w*v||^2 analytically
      const float ny = sqrtf(fmaxf(yn_raw, EPS2));
      const float sy = (ny >= MAXN) ? (MAXN * __builtin_amdgcn_rcpf(ny + EPS)) : 1.0f;
      const float sw = sy * wgt;
      const float xy = sw * pp;
      const float yn = (sy * sy) * yn_raw;
      const float Af = 1.0f + 2.0f * xy + yn;
      const float Cf = 1.0f - xn;
      const float den = 1.0f + 2.0f * xy + xn * yn + EPS;
      float id = __builtin_amdgcn_rcpf(den);
      id = id * (2.0f - den * id);            // 1 NR step -> fp32-accurate
      const float on_raw = (Af * Af * xn + 2.0f * Af * Cf * xy + Cf * Cf * yn) * (id * id);
      const float no = sqrtf(fmaxf(on_raw, EPS2));
      const float so = (no >= MAXN) ? (MAXN * __builtin_amdgcn_rcpf(no + EPS)) : 1.0f;
      const float ms = id * so;
      const float am = Af * ms, cm = Cf * sw * ms;
      ws0 = am * ws0 + cm * va.x; ws1 = am * ws1 + cm * va.y;
      ws2 = am * ws2 + cm * va.z; ws3 = am * ws3 + cm * va.w;
      ws4 = am * ws4 + cm * vb.x; ws5 = am * ws5 + cm * vb.y;
      ws6 = am * ws6 + cm * vb.z; ws7 = am * ws7 + cm * vb.w;
      xn = on_raw * (so * so);                // ||projected out||^2, analytic
    }
    __syncthreads();
  }
  float* o = att + (((size_t)bh * 512 + i0 + i_local) * 64 + d0);
  float4 st1; st1.x = ws0; st1.y = ws1; st1.z = ws2; st1.w = ws3;
  float4 st2; st2.x = ws4; st2.y = ws5; st2.z = ws6; st2.w = ws7;
  *(float4*)&o[0] = st1;
  *(float4*)&o[4] = st2;
}

extern "C" void kernel_launch(void* const* d_in, const int* in_sizes, int n_in,
                              void* d_out, int out_size, void* d_ws, size_t ws_size,
                              hipStream_t stream) {
  const float* query = (const float*)d_in[0];
  const float* key_  = (const float*)d_in[1];
  const float* value = (const float*)d_in[2];
  const float* Wq = (const float*)d_in[3];
  const float* bq = (const float*)d_in[4];
  const float* Wk = (const float*)d_in[5];
  const float* bk = (const float*)d_in[6];
  const float* Wv = (const float*)d_in[7];
  const float* bv = (const float*)d_in[8];
  const float* Wo = (const float*)d_in[9];
  const float* bo = (const float*)d_in[10];
  float* ws = (float*)d_ws;
  const size_t M = 1u << 20;          // 1M floats
  float* Qb   = ws;                   // [32,512,64]
  float* Kb   = ws + 1 * M;
  float* Vb   = ws + 2 * M;
  float* qn   = ws + 3 * M;           // [32,512]
  float* kn   = qn + 16384;
  float* vn   = kn + 16384;
  float* attn = ws + 4 * M;           // [32,512,512] (8M floats)
  float* xt3  = ws + 12 * M;          // 3x [2048,512]
  float* t3   = ws + 15 * M;          // 3x [2048,512]   (peak: 72 MB)
  float* att  = ws + 12 * M;          // reuse xt3 region after QKV done
  float* xto  = ws + 13 * M;
  float* to_  = ws + 14 * M;

  // Q/K/V hyperbolic linears
  k_logmap<<<dim3(2048, 3), 256, 0, stream>>>(query, key_, value, xt3, 0);
  k_gemm<<<dim3(32, 8, 3), 256, 0, stream>>>(xt3, Wq, Wk, Wv, t3);
  k_post<<<dim3(2048, 3), 256, 0, stream>>>(t3, bq, bk, bv, Qb, Kb, Vb, qn, kn, vn, 0);
  // distances + softmax
  k_logits<<<dim3(8, 4, 32), 256, 0, stream>>>(Qb, Kb, qn, kn, attn);
  k_softmax<<<16384, 256, 0, stream>>>(attn);
  // sequential mobius aggregation
  k_scan<<<512, 256, 0, stream>>>(Vb, vn, attn, att);
  // output hyperbolic linear
  k_logmap<<<dim3(2048, 1), 256, 0, stream>>>(att, att, att, xto, 1);
  k_gemm<<<dim3(32, 8, 1), 256, 0, stream>>>(xto, Wo, Wo, Wo, to_);
  k_post<<<dim3(2048, 1), 256, 0, stream>>>(to_, bo, bo, bo, (float*)d_out,
                                            nullptr, nullptr, nullptr, nullptr, nullptr, 1);
}